// Round 1
// baseline (325.800 us; speedup 1.0000x reference)
//
#include <hip/hip_runtime.h>
#include <hip/hip_bf16.h>
#include <hip/hip_fp16.h>
#include <type_traits>

// f32 in / f32 out. Round-4: (1) GRID 512->1024 (4 blocks/CU = 32 waves/CU max
// occupancy; was 2 blocks/CU, Occupancy 37%); (2) z pre-converted to fp16 in
// d_ws by a BW-bound pre-pass, main kernel gathers half the bytes, multiplies
// with packed v_pk_mul_f16 and uses f16 MFMA (also better accuracy than bf16).
// Software-pipelined gather (edge idx 2 tiles ahead, z rows 1 tile ahead),
// double-buffered LDS, ONE barrier per tile, 32 hidden cols per wave.

#define N_NODES 100000
#define N_EDGES 500000
#define D_IN    128
#define D_HID   256
#define M_TILE  32
#define NTILES  (N_EDGES / M_TILE)   // 15625 exactly, no partial tile
#define LDS_STRIDE 136               // 128 + 8 elements pad (2B elements)
#define GRID    1024                 // 4 blocks/CU resident target

typedef _Float16 half8  __attribute__((ext_vector_type(8)));
typedef __bf16   bf16x8 __attribute__((ext_vector_type(8)));
typedef float    f32x4  __attribute__((ext_vector_type(4)));
typedef float    f32x2  __attribute__((ext_vector_type(2)));

union F4H { float4 v; f32x2 h[2]; };

__device__ __forceinline__ unsigned int pkbf(f32x2 q) {
    union { __hip_bfloat162 b; unsigned int u; } c;
    c.b = __float22bfloat162_rn(make_float2(q.x, q.y));   // RNE packed cvt
    return c.u;
}

// mish(x) = x * N/(N+2), N = E*(E+2), E = e^x — float2-vectorized
__device__ __forceinline__ f32x2 mish2(f32x2 x) {
    f32x2 xc = {fminf(x.x, 20.0f), fminf(x.y, 20.0f)};
    f32x2 E  = {__expf(xc.x), __expf(xc.y)};
    f32x2 num = E * (E + 2.0f);
    f32x2 den = num + 2.0f;
    f32x2 r  = {__builtin_amdgcn_rcpf(den.x), __builtin_amdgcn_rcpf(den.y)};
    return x * num * r;
}

// ---- pre-pass: z f32 -> fp16 (RNE), fully coalesced, BW-bound ----
// N_NODES*D_IN = 12.8M elems = 1.6M chunks of 8; grid 6250 x 256 exact.
__global__ __launch_bounds__(256)
void zcvt_kernel(const float* __restrict__ z, _Float16* __restrict__ zh) {
    const size_t i = (size_t)blockIdx.x * 256 + threadIdx.x;   // chunk id
    const float4 f0 = *reinterpret_cast<const float4*>(z + i * 8);
    const float4 f1 = *reinterpret_cast<const float4*>(z + i * 8 + 4);
    union { half8 h; uint4 u; } o;
    o.h[0] = (_Float16)f0.x; o.h[1] = (_Float16)f0.y;
    o.h[2] = (_Float16)f0.z; o.h[3] = (_Float16)f0.w;
    o.h[4] = (_Float16)f1.x; o.h[5] = (_Float16)f1.y;
    o.h[6] = (_Float16)f1.z; o.h[7] = (_Float16)f1.w;
    *reinterpret_cast<uint4*>(zh + i * 8) = o.u;
}

template <bool USE_H>
__global__ __launch_bounds__(512, 8)
void edge_decoder_kernel(const float*    __restrict__ z,
                         const _Float16* __restrict__ zh,
                         const int*      __restrict__ edge,
                         const float*    __restrict__ W1,
                         const float*    __restrict__ b1,
                         const float*    __restrict__ W2,
                         const float*    __restrict__ b2,
                         float*          __restrict__ out) {
    using frag_t = std::conditional_t<USE_H, half8, bf16x8>;

    __shared__ ushort xbuf[2][M_TILE * LDS_STRIDE];   // 2 x 8.7 KB
    __shared__ float  lpart[2][8][M_TILE];            // 2 KB

    const int t    = threadIdx.x;
    const int wave = t >> 6;          // 0..7
    const int lane = t & 63;
    const int quad = lane >> 4;
    const int nlo  = lane & 15;

    // ---- W1 -> B-fragments (wave owns hidden cols [32w, 32w+32)) ----
    frag_t bfrag[4][2];               // [ks][nt] = 32 VGPRs
    float  b1f[2], w2f[2];
    #pragma unroll
    for (int nt = 0; nt < 2; ++nt) {
        const int n = wave * 32 + nt * 16 + nlo;
        const float* wrow = W1 + n * D_IN;
        #pragma unroll
        for (int ks = 0; ks < 4; ++ks) {
            float4 w0 = *reinterpret_cast<const float4*>(wrow + ks * 32 + quad * 8);
            float4 w1 = *reinterpret_cast<const float4*>(wrow + ks * 32 + quad * 8 + 4);
            float wa[8] = {w0.x, w0.y, w0.z, w0.w, w1.x, w1.y, w1.z, w1.w};
            if constexpr (USE_H) {
                half8 hv;
                #pragma unroll
                for (int j = 0; j < 8; ++j) hv[j] = (_Float16)wa[j];
                bfrag[ks][nt] = hv;
            } else {
                bf16x8 bv;
                #pragma unroll
                for (int j = 0; j < 8; ++j) bv[j] = (__bf16)wa[j];
                bfrag[ks][nt] = bv;
            }
        }
        b1f[nt] = b1[n];
        w2f[nt] = W2[n];
    }
    const float b2f = b2[0];

    // ---- gather assignment: slot = edge within tile, cch = 8-elem chunk ----
    const int s_slot = t >> 4;        // 0..31
    const int cch    = t & 15;        // 0..15

    // ---- pipeline prologue ----
    int tile = blockIdx.x;
    float4 a0, a1, c0, c1;            // f32 path gather regs
    half8  ha, hc;                    // fp16 path gather regs
    {
        const int e = tile * M_TILE + s_slot;
        const int u = edge[e], v = edge[N_EDGES + e];
        if constexpr (USE_H) {
            ha = *reinterpret_cast<const half8*>(zh + (size_t)u * D_IN + cch * 8);
            hc = *reinterpret_cast<const half8*>(zh + (size_t)v * D_IN + cch * 8);
        } else {
            const float* zu = z + (size_t)u * D_IN + cch * 8;
            const float* zv = z + (size_t)v * D_IN + cch * 8;
            a0 = *reinterpret_cast<const float4*>(zu);
            a1 = *reinterpret_cast<const float4*>(zu + 4);
            c0 = *reinterpret_cast<const float4*>(zv);
            c1 = *reinterpret_cast<const float4*>(zv + 4);
        }
    }
    // edge indices for tile+GRID
    int u_n, v_n;
    {
        const int t1 = min(tile + GRID, NTILES - 1);
        const int e1 = t1 * M_TILE + s_slot;
        u_n = edge[e1]; v_n = edge[N_EDGES + e1];
    }

    int  p = 0;
    bool have_prev = false;
    int  prev_base = 0;

    for (; tile < NTILES; tile += GRID) {
        // ---- A: current tile's gathered pair-product -> xbuf[p] ----
        if constexpr (USE_H) {
            union { half8 h; uint4 u; } pr;
            pr.h = ha * hc;                       // 4x v_pk_mul_f16
            *reinterpret_cast<uint4*>(&xbuf[p][s_slot * LDS_STRIDE + cch * 8]) = pr.u;
        } else {
            F4H A0{a0}, A1{a1}, C0{c0}, C1{c1};
            unsigned int r0 = pkbf(A0.h[0] * C0.h[0]);
            unsigned int r1 = pkbf(A0.h[1] * C0.h[1]);
            unsigned int r2 = pkbf(A1.h[0] * C1.h[0]);
            unsigned int r3 = pkbf(A1.h[1] * C1.h[1]);
            *reinterpret_cast<uint4*>(&xbuf[p][s_slot * LDS_STRIDE + cch * 8]) =
                make_uint4(r0, r1, r2, r3);
        }
        // ---- B: the single barrier ----
        __syncthreads();

        // ---- C: issue next tile's z loads (indices already resident) +
        //          edge-index loads 2 tiles ahead ----
        if constexpr (USE_H) {
            ha = *reinterpret_cast<const half8*>(zh + (size_t)u_n * D_IN + cch * 8);
            hc = *reinterpret_cast<const half8*>(zh + (size_t)v_n * D_IN + cch * 8);
        } else {
            const float* zu = z + (size_t)u_n * D_IN + cch * 8;
            const float* zv = z + (size_t)v_n * D_IN + cch * 8;
            a0 = *reinterpret_cast<const float4*>(zu);
            a1 = *reinterpret_cast<const float4*>(zu + 4);
            c0 = *reinterpret_cast<const float4*>(zv);
            c1 = *reinterpret_cast<const float4*>(zv + 4);
        }
        {
            const int t2 = min(tile + 2 * GRID, NTILES - 1);
            const int e2 = t2 * M_TILE + s_slot;
            u_n = edge[e2]; v_n = edge[N_EDGES + e2];
        }

        // ---- E: combine + store PREVIOUS tile (lpart[p^1] sealed by barrier) ----
        if (have_prev) {
            if (t < M_TILE) {
                const int pp = p ^ 1;
                float logit = b2f;
                #pragma unroll
                for (int w = 0; w < 8; ++w) logit += lpart[pp][w][t];
                out[prev_base + t] = __builtin_amdgcn_rcpf(1.0f + __expf(-logit));
            }
        }

        // ---- D: MFMA + epilogue for current tile -> lpart[p] ----
        f32x4 acc[2][2];
        #pragma unroll
        for (int mt = 0; mt < 2; ++mt)
            #pragma unroll
            for (int nt = 0; nt < 2; ++nt)
                acc[mt][nt] = (f32x4){0.f, 0.f, 0.f, 0.f};

        #pragma unroll
        for (int ks = 0; ks < 4; ++ks) {
            frag_t af[2];
            #pragma unroll
            for (int mt = 0; mt < 2; ++mt)
                af[mt] = *reinterpret_cast<const frag_t*>(
                    &xbuf[p][(mt * 16 + nlo) * LDS_STRIDE + ks * 32 + quad * 8]);
            #pragma unroll
            for (int mt = 0; mt < 2; ++mt)
                #pragma unroll
                for (int nt = 0; nt < 2; ++nt) {
                    if constexpr (USE_H)
                        acc[mt][nt] = __builtin_amdgcn_mfma_f32_16x16x32_f16(
                            af[mt], bfrag[ks][nt], acc[mt][nt], 0, 0, 0);
                    else
                        acc[mt][nt] = __builtin_amdgcn_mfma_f32_16x16x32_bf16(
                            af[mt], bfrag[ks][nt], acc[mt][nt], 0, 0, 0);
                }
        }

        // D layout: row = mt*16 + quad*4 + r, col = nlo + 16nt (+32*wave)
        #pragma unroll
        for (int mt = 0; mt < 2; ++mt) {
            #pragma unroll
            for (int pr = 0; pr < 2; ++pr) {
                f32x2 s2 = {0.f, 0.f};
                #pragma unroll
                for (int nt = 0; nt < 2; ++nt) {
                    f32x2 h = {acc[mt][nt][2 * pr]     + b1f[nt],
                               acc[mt][nt][2 * pr + 1] + b1f[nt]};
                    f32x2 m = mish2(h);
                    s2.x += m.x * w2f[nt];
                    s2.y += m.y * w2f[nt];
                }
                float sx = s2.x, sy = s2.y;
                sx += __shfl_xor(sx, 1); sy += __shfl_xor(sy, 1);
                sx += __shfl_xor(sx, 2); sy += __shfl_xor(sy, 2);
                sx += __shfl_xor(sx, 4); sy += __shfl_xor(sy, 4);
                sx += __shfl_xor(sx, 8); sy += __shfl_xor(sy, 8);
                if (nlo == 0) {
                    const int row = mt * 16 + quad * 4 + pr * 2;
                    lpart[p][wave][row]     = sx;
                    lpart[p][wave][row + 1] = sy;
                }
            }
        }

        have_prev = true;
        prev_base = tile * M_TILE;
        p ^= 1;
    }

    // ---- drain: last tile's logits ----
    __syncthreads();
    if (have_prev && t < M_TILE) {
        const int pp = p ^ 1;
        float logit = b2f;
        #pragma unroll
        for (int w = 0; w < 8; ++w) logit += lpart[pp][w][t];
        out[prev_base + t] = __builtin_amdgcn_rcpf(1.0f + __expf(-logit));
    }
}

extern "C" void kernel_launch(void* const* d_in, const int* in_sizes, int n_in,
                              void* d_out, int out_size, void* d_ws, size_t ws_size,
                              hipStream_t stream) {
    const float* z    = (const float*)d_in[0];
    const int*   edge = (const int*)d_in[1];
    const float* W1   = (const float*)d_in[2];
    const float* b1   = (const float*)d_in[3];
    const float* W2   = (const float*)d_in[4];
    const float* b2   = (const float*)d_in[5];
    float* out = (float*)d_out;

    const size_t zh_bytes = (size_t)N_NODES * D_IN * sizeof(_Float16);  // 25.6 MB
    if (d_ws != nullptr && ws_size >= zh_bytes) {
        _Float16* zh = (_Float16*)d_ws;
        zcvt_kernel<<<dim3(N_NODES * D_IN / 8 / 256), dim3(256), 0, stream>>>(z, zh);
        edge_decoder_kernel<true><<<dim3(GRID), dim3(512), 0, stream>>>(
            z, zh, edge, W1, b1, W2, b2, out);
    } else {
        edge_decoder_kernel<false><<<dim3(GRID), dim3(512), 0, stream>>>(
            z, nullptr, edge, W1, b1, W2, b2, out);
    }
}

// Round 2
// 182.720 us; speedup vs baseline: 1.7831x; 1.7831x over previous
//
#include <hip/hip_runtime.h>
#include <hip/hip_bf16.h>
#include <hip/hip_fp16.h>
#include <type_traits>

// f32 in / f32 out. Round-5: round-4's __launch_bounds__(512,8) crushed the
// allocator to 32 VGPR -> 133 MB scratch spill (WRITE_SIZE counter). Revert to
// (512,4): natural allocation ~52-60 VGPR is <=64, so 8 waves/SIMD (4 blocks/CU)
// still fits at runtime WITHOUT spills. Keep GRID=1024 (4 blocks/CU launched)
// and the fp16 z pre-pass (half gather bytes, packed v_pk_mul_f16, f16 MFMA).
// Software-pipelined gather, double-buffered LDS, ONE barrier per tile.

#define N_NODES 100000
#define N_EDGES 500000
#define D_IN    128
#define D_HID   256
#define M_TILE  32
#define NTILES  (N_EDGES / M_TILE)   // 15625 exactly, no partial tile
#define LDS_STRIDE 136               // 128 + 8 elements pad (2B elements)
#define GRID    1024                 // 4 blocks/CU resident target

typedef _Float16 half8  __attribute__((ext_vector_type(8)));
typedef __bf16   bf16x8 __attribute__((ext_vector_type(8)));
typedef float    f32x4  __attribute__((ext_vector_type(4)));
typedef float    f32x2  __attribute__((ext_vector_type(2)));

union F4H { float4 v; f32x2 h[2]; };

__device__ __forceinline__ unsigned int pkbf(f32x2 q) {
    union { __hip_bfloat162 b; unsigned int u; } c;
    c.b = __float22bfloat162_rn(make_float2(q.x, q.y));   // RNE packed cvt
    return c.u;
}

// mish(x) = x * N/(N+2), N = E*(E+2), E = e^x — float2-vectorized
__device__ __forceinline__ f32x2 mish2(f32x2 x) {
    f32x2 xc = {fminf(x.x, 20.0f), fminf(x.y, 20.0f)};
    f32x2 E  = {__expf(xc.x), __expf(xc.y)};
    f32x2 num = E * (E + 2.0f);
    f32x2 den = num + 2.0f;
    f32x2 r  = {__builtin_amdgcn_rcpf(den.x), __builtin_amdgcn_rcpf(den.y)};
    return x * num * r;
}

// ---- pre-pass: z f32 -> fp16 (RNE), fully coalesced, BW-bound ----
// N_NODES*D_IN = 12.8M elems = 1.6M chunks of 8; grid 6250 x 256 exact.
__global__ __launch_bounds__(256)
void zcvt_kernel(const float* __restrict__ z, _Float16* __restrict__ zh) {
    const size_t i = (size_t)blockIdx.x * 256 + threadIdx.x;   // chunk id
    const float4 f0 = *reinterpret_cast<const float4*>(z + i * 8);
    const float4 f1 = *reinterpret_cast<const float4*>(z + i * 8 + 4);
    union { half8 h; uint4 u; } o;
    o.h[0] = (_Float16)f0.x; o.h[1] = (_Float16)f0.y;
    o.h[2] = (_Float16)f0.z; o.h[3] = (_Float16)f0.w;
    o.h[4] = (_Float16)f1.x; o.h[5] = (_Float16)f1.y;
    o.h[6] = (_Float16)f1.z; o.h[7] = (_Float16)f1.w;
    *reinterpret_cast<uint4*>(zh + i * 8) = o.u;
}

template <bool USE_H>
__global__ __launch_bounds__(512, 4)
void edge_decoder_kernel(const float*    __restrict__ z,
                         const _Float16* __restrict__ zh,
                         const int*      __restrict__ edge,
                         const float*    __restrict__ W1,
                         const float*    __restrict__ b1,
                         const float*    __restrict__ W2,
                         const float*    __restrict__ b2,
                         float*          __restrict__ out) {
    using frag_t = std::conditional_t<USE_H, half8, bf16x8>;

    __shared__ ushort xbuf[2][M_TILE * LDS_STRIDE];   // 2 x 8.7 KB
    __shared__ float  lpart[2][8][M_TILE];            // 2 KB

    const int t    = threadIdx.x;
    const int wave = t >> 6;          // 0..7
    const int lane = t & 63;
    const int quad = lane >> 4;
    const int nlo  = lane & 15;

    // ---- W1 -> B-fragments (wave owns hidden cols [32w, 32w+32)) ----
    frag_t bfrag[4][2];               // [ks][nt] = 32 VGPRs
    float  b1f[2], w2f[2];
    #pragma unroll
    for (int nt = 0; nt < 2; ++nt) {
        const int n = wave * 32 + nt * 16 + nlo;
        const float* wrow = W1 + n * D_IN;
        #pragma unroll
        for (int ks = 0; ks < 4; ++ks) {
            float4 w0 = *reinterpret_cast<const float4*>(wrow + ks * 32 + quad * 8);
            float4 w1 = *reinterpret_cast<const float4*>(wrow + ks * 32 + quad * 8 + 4);
            float wa[8] = {w0.x, w0.y, w0.z, w0.w, w1.x, w1.y, w1.z, w1.w};
            if constexpr (USE_H) {
                half8 hv;
                #pragma unroll
                for (int j = 0; j < 8; ++j) hv[j] = (_Float16)wa[j];
                bfrag[ks][nt] = hv;
            } else {
                bf16x8 bv;
                #pragma unroll
                for (int j = 0; j < 8; ++j) bv[j] = (__bf16)wa[j];
                bfrag[ks][nt] = bv;
            }
        }
        b1f[nt] = b1[n];
        w2f[nt] = W2[n];
    }
    const float b2f = b2[0];

    // ---- gather assignment: slot = edge within tile, cch = 8-elem chunk ----
    const int s_slot = t >> 4;        // 0..31
    const int cch    = t & 15;        // 0..15

    // ---- pipeline prologue ----
    int tile = blockIdx.x;
    float4 a0, a1, c0, c1;            // f32 path gather regs
    half8  ha, hc;                    // fp16 path gather regs
    {
        const int e = tile * M_TILE + s_slot;
        const int u = edge[e], v = edge[N_EDGES + e];
        if constexpr (USE_H) {
            ha = *reinterpret_cast<const half8*>(zh + (size_t)u * D_IN + cch * 8);
            hc = *reinterpret_cast<const half8*>(zh + (size_t)v * D_IN + cch * 8);
        } else {
            const float* zu = z + (size_t)u * D_IN + cch * 8;
            const float* zv = z + (size_t)v * D_IN + cch * 8;
            a0 = *reinterpret_cast<const float4*>(zu);
            a1 = *reinterpret_cast<const float4*>(zu + 4);
            c0 = *reinterpret_cast<const float4*>(zv);
            c1 = *reinterpret_cast<const float4*>(zv + 4);
        }
    }
    // edge indices for tile+GRID
    int u_n, v_n;
    {
        const int t1 = min(tile + GRID, NTILES - 1);
        const int e1 = t1 * M_TILE + s_slot;
        u_n = edge[e1]; v_n = edge[N_EDGES + e1];
    }

    int  p = 0;
    bool have_prev = false;
    int  prev_base = 0;

    for (; tile < NTILES; tile += GRID) {
        // ---- A: current tile's gathered pair-product -> xbuf[p] ----
        if constexpr (USE_H) {
            union { half8 h; uint4 u; } pr;
            pr.h = ha * hc;                       // 4x v_pk_mul_f16
            *reinterpret_cast<uint4*>(&xbuf[p][s_slot * LDS_STRIDE + cch * 8]) = pr.u;
        } else {
            F4H A0{a0}, A1{a1}, C0{c0}, C1{c1};
            unsigned int r0 = pkbf(A0.h[0] * C0.h[0]);
            unsigned int r1 = pkbf(A0.h[1] * C0.h[1]);
            unsigned int r2 = pkbf(A1.h[0] * C1.h[0]);
            unsigned int r3 = pkbf(A1.h[1] * C1.h[1]);
            *reinterpret_cast<uint4*>(&xbuf[p][s_slot * LDS_STRIDE + cch * 8]) =
                make_uint4(r0, r1, r2, r3);
        }
        // ---- B: the single barrier ----
        __syncthreads();

        // ---- C: issue next tile's z loads (indices already resident) +
        //          edge-index loads 2 tiles ahead ----
        if constexpr (USE_H) {
            ha = *reinterpret_cast<const half8*>(zh + (size_t)u_n * D_IN + cch * 8);
            hc = *reinterpret_cast<const half8*>(zh + (size_t)v_n * D_IN + cch * 8);
        } else {
            const float* zu = z + (size_t)u_n * D_IN + cch * 8;
            const float* zv = z + (size_t)v_n * D_IN + cch * 8;
            a0 = *reinterpret_cast<const float4*>(zu);
            a1 = *reinterpret_cast<const float4*>(zu + 4);
            c0 = *reinterpret_cast<const float4*>(zv);
            c1 = *reinterpret_cast<const float4*>(zv + 4);
        }
        {
            const int t2 = min(tile + 2 * GRID, NTILES - 1);
            const int e2 = t2 * M_TILE + s_slot;
            u_n = edge[e2]; v_n = edge[N_EDGES + e2];
        }

        // ---- E: combine + store PREVIOUS tile (lpart[p^1] sealed by barrier) ----
        if (have_prev) {
            if (t < M_TILE) {
                const int pp = p ^ 1;
                float logit = b2f;
                #pragma unroll
                for (int w = 0; w < 8; ++w) logit += lpart[pp][w][t];
                out[prev_base + t] = __builtin_amdgcn_rcpf(1.0f + __expf(-logit));
            }
        }

        // ---- D: MFMA + epilogue for current tile -> lpart[p] ----
        f32x4 acc[2][2];
        #pragma unroll
        for (int mt = 0; mt < 2; ++mt)
            #pragma unroll
            for (int nt = 0; nt < 2; ++nt)
                acc[mt][nt] = (f32x4){0.f, 0.f, 0.f, 0.f};

        #pragma unroll
        for (int ks = 0; ks < 4; ++ks) {
            frag_t af[2];
            #pragma unroll
            for (int mt = 0; mt < 2; ++mt)
                af[mt] = *reinterpret_cast<const frag_t*>(
                    &xbuf[p][(mt * 16 + nlo) * LDS_STRIDE + ks * 32 + quad * 8]);
            #pragma unroll
            for (int mt = 0; mt < 2; ++mt)
                #pragma unroll
                for (int nt = 0; nt < 2; ++nt) {
                    if constexpr (USE_H)
                        acc[mt][nt] = __builtin_amdgcn_mfma_f32_16x16x32_f16(
                            af[mt], bfrag[ks][nt], acc[mt][nt], 0, 0, 0);
                    else
                        acc[mt][nt] = __builtin_amdgcn_mfma_f32_16x16x32_bf16(
                            af[mt], bfrag[ks][nt], acc[mt][nt], 0, 0, 0);
                }
        }

        // D layout: row = mt*16 + quad*4 + r, col = nlo + 16nt (+32*wave)
        #pragma unroll
        for (int mt = 0; mt < 2; ++mt) {
            #pragma unroll
            for (int pr = 0; pr < 2; ++pr) {
                f32x2 s2 = {0.f, 0.f};
                #pragma unroll
                for (int nt = 0; nt < 2; ++nt) {
                    f32x2 h = {acc[mt][nt][2 * pr]     + b1f[nt],
                               acc[mt][nt][2 * pr + 1] + b1f[nt]};
                    f32x2 m = mish2(h);
                    s2.x += m.x * w2f[nt];
                    s2.y += m.y * w2f[nt];
                }
                float sx = s2.x, sy = s2.y;
                sx += __shfl_xor(sx, 1); sy += __shfl_xor(sy, 1);
                sx += __shfl_xor(sx, 2); sy += __shfl_xor(sy, 2);
                sx += __shfl_xor(sx, 4); sy += __shfl_xor(sy, 4);
                sx += __shfl_xor(sx, 8); sy += __shfl_xor(sy, 8);
                if (nlo == 0) {
                    const int row = mt * 16 + quad * 4 + pr * 2;
                    lpart[p][wave][row]     = sx;
                    lpart[p][wave][row + 1] = sy;
                }
            }
        }

        have_prev = true;
        prev_base = tile * M_TILE;
        p ^= 1;
    }

    // ---- drain: last tile's logits ----
    __syncthreads();
    if (have_prev && t < M_TILE) {
        const int pp = p ^ 1;
        float logit = b2f;
        #pragma unroll
        for (int w = 0; w < 8; ++w) logit += lpart[pp][w][t];
        out[prev_base + t] = __builtin_amdgcn_rcpf(1.0f + __expf(-logit));
    }
}

extern "C" void kernel_launch(void* const* d_in, const int* in_sizes, int n_in,
                              void* d_out, int out_size, void* d_ws, size_t ws_size,
                              hipStream_t stream) {
    const float* z    = (const float*)d_in[0];
    const int*   edge = (const int*)d_in[1];
    const float* W1   = (const float*)d_in[2];
    const float* b1   = (const float*)d_in[3];
    const float* W2   = (const float*)d_in[4];
    const float* b2   = (const float*)d_in[5];
    float* out = (float*)d_out;

    const size_t zh_bytes = (size_t)N_NODES * D_IN * sizeof(_Float16);  // 25.6 MB
    if (d_ws != nullptr && ws_size >= zh_bytes) {
        _Float16* zh = (_Float16*)d_ws;
        zcvt_kernel<<<dim3(N_NODES * D_IN / 8 / 256), dim3(256), 0, stream>>>(z, zh);
        edge_decoder_kernel<true><<<dim3(GRID), dim3(512), 0, stream>>>(
            z, zh, edge, W1, b1, W2, b2, out);
    } else {
        edge_decoder_kernel<false><<<dim3(GRID), dim3(512), 0, stream>>>(
            z, nullptr, edge, W1, b1, W2, b2, out);
    }
}